// Round 1
// baseline (351.527 us; speedup 1.0000x reference)
//
#include <hip/hip_runtime.h>
#include <stdint.h>

typedef unsigned short u16;
typedef unsigned int   u32;
typedef __attribute__((ext_vector_type(8))) short  short8;   // 8 x bf16 (4 VGPRs)
typedef __attribute__((ext_vector_type(4))) float  floatx4;  // MFMA acc

__device__ __forceinline__ u16 f32_to_bf16(float f) {
  u32 u = __builtin_bit_cast(u32, f);
  u = (u + 0x7fffu + ((u >> 16) & 1u)) >> 16;
  return (u16)u;
}
__device__ __forceinline__ float bf16_to_f32(u16 h) {
  u32 u = ((u32)h) << 16;
  return __builtin_bit_cast(float, u);
}

// async global->LDS, 16B per lane. LDS dst = wave-uniform base + lane*16.
__device__ __forceinline__ void load_lds16(const u16* g, u16* l) {
  auto gp = (const __attribute__((address_space(1))) u32*)(uintptr_t)g;
  auto lp = (__attribute__((address_space(3))) u32*)(u32)(uintptr_t)l;
  __builtin_amdgcn_global_load_lds(gp, lp, 16, 0, 0);
}

// ---------------------------------------------------------------------------
// K1: fused QKV 1x1 conv + patch-token layout.
// qt,kt: [b][n][m] bf16 (n=token 0..1023, m=chan 0..511, K-contiguous in m)
// v:     [b][m][n] bf16
// m = cq*64 + wp*2 + (hp>>4); n = (hp&15)*64 + p1*8 + p2; w=wp*8+p1, h=hp*8+p2
// WG: (wq,g,b). covers w in [32wq,32wq+32), h in [16g,16g+16) U [128+16g,...)
// ---------------------------------------------------------------------------
__global__ __launch_bounds__(1024) void qkv_kernel(
    const float* __restrict__ x,
    const float* __restrict__ Wq, const float* __restrict__ bq,
    const float* __restrict__ Wk, const float* __restrict__ bk,
    const float* __restrict__ Wv, const float* __restrict__ bv,
    u16* __restrict__ qt, u16* __restrict__ kt, u16* __restrict__ vm)
{
  __shared__ __align__(16) u16 qs[128 * 64];   // [nl][cq*8+mc]
  __shared__ __align__(16) u16 ks_[128 * 64];
  __shared__ __align__(16) u16 vs[64 * 128];   // [cq*8+mc][nl]

  const int wq = blockIdx.x;   // 0..7
  const int g  = blockIdx.y;   // 0..7
  const int b  = blockIdx.z;   // 0..7
  const int t  = threadIdx.x;
  const int lw = t >> 5, lh = t & 31;
  const int w  = wq * 32 + lw;
  const int h  = g * 16 + (lh & 15) + ((lh >> 4) << 7);
  const int nl = ((lh >> 3) & 1) * 64 + (lw & 7) * 8 + (lh & 7);  // 0..127
  const int mc = ((lw >> 3) << 1) + (lh >> 4);                    // 0..7

  float aq[8], ak[8], av[8];
#pragma unroll
  for (int i = 0; i < 8; i++) { aq[i] = 0.f; ak[i] = 0.f; av[i] = 0.f; }

  const float* xp = x + (size_t)b * 64 * 65536 + w * 256 + h;
#pragma unroll 4
  for (int c = 0; c < 64; c++) {
    float xv = xp[c * 65536];
#pragma unroll
    for (int cq = 0; cq < 8; cq++) {
      aq[cq] = fmaf(Wq[cq * 64 + c], xv, aq[cq]);
      ak[cq] = fmaf(Wk[cq * 64 + c], xv, ak[cq]);
      av[cq] = fmaf(Wv[cq * 64 + c], xv, av[cq]);
    }
  }
#pragma unroll
  for (int cq = 0; cq < 8; cq++) {
    qs[nl * 64 + cq * 8 + mc]  = f32_to_bf16(aq[cq] + bq[cq]);
    ks_[nl * 64 + cq * 8 + mc] = f32_to_bf16(ak[cq] + bk[cq]);
    vs[(cq * 8 + mc) * 128 + nl] = f32_to_bf16(av[cq] + bv[cq]);
  }
  __syncthreads();

  // qt/kt: thread -> (nl2 = t>>3, cq2 = t&7) writes 16B chunk (8 m-values)
  {
    const int nl2 = t >> 3, cq2 = t & 7;
    const size_t row = (size_t)b * 1024 + g * 128 + nl2;
    uint4 vq = *(const uint4*)(qs + nl2 * 64 + cq2 * 8);
    uint4 vk = *(const uint4*)(ks_ + nl2 * 64 + cq2 * 8);
    *(uint4*)(qt + row * 512 + cq2 * 64 + wq * 8) = vq;
    *(uint4*)(kt + row * 512 + cq2 * 64 + wq * 8) = vk;
  }
  // v: thread -> (pr = t>>4, l16 = t&15), row m, 128-contig n chunk
  {
    const int pr = t >> 4, l16 = t & 15;
    const int cq3 = pr >> 3, mc3 = pr & 7;
    const int mrow = cq3 * 64 + wq * 8 + mc3;
    uint4 vv = *(const uint4*)(vs + pr * 128 + l16 * 8);
    *(uint4*)(vm + ((size_t)b * 512 + mrow) * 1024 + g * 128 + l16 * 8) = vv;
  }
}

// ---------------------------------------------------------------------------
// NT GEMM: C[M][N] = scale * A[M][K] * B[N][K]^T   (all bf16, fp32 acc)
// m97 structure: 128x128 tile, BK=64, 4 waves each 64x64 (4x4 frags of 16x16)
// ---------------------------------------------------------------------------
__global__ __launch_bounds__(256) void gemm_nt(
    const u16* __restrict__ A, const u16* __restrict__ Bm, u16* __restrict__ Cm,
    int M, int N, int K, float scale)
{
  __shared__ __align__(16) u16 As[128 * 64];
  __shared__ __align__(16) u16 Bs[128 * 64];

  const int bn = blockIdx.x, bm = blockIdx.y, bz = blockIdx.z;
  const int t = threadIdx.x;
  const int lane = t & 63, wid = t >> 6;
  const int wm = wid & 1, wn = wid >> 1;
  const int m0 = bm * 128, n0 = bn * 128;

  const u16* Ab = A + (size_t)bz * M * K + (size_t)m0 * K;
  const u16* Bb = Bm + (size_t)bz * N * K + (size_t)n0 * K;

  floatx4 acc[4][4];
#pragma unroll
  for (int i = 0; i < 4; i++)
#pragma unroll
    for (int j = 0; j < 4; j++) acc[i][j] = (floatx4){0.f, 0.f, 0.f, 0.f};

  const int srow = wid * 8 + (lane >> 3);   // staging row within 32-row group
  const int scol = (lane & 7) * 8;

  for (int k0 = 0; k0 < K; k0 += 64) {
#pragma unroll
    for (int i = 0; i < 4; i++) {
      int row = i * 32 + srow;
      load_lds16(Ab + (size_t)row * K + k0 + scol, As + (i * 32 + wid * 8) * 64);
      load_lds16(Bb + (size_t)row * K + k0 + scol, Bs + (i * 32 + wid * 8) * 64);
    }
    __syncthreads();
#pragma unroll
    for (int ks = 0; ks < 2; ks++) {
      const int koff = ks * 32 + (lane >> 4) * 8;
      short8 a[4], b[4];
#pragma unroll
      for (int f = 0; f < 4; f++) {
        a[f] = *(const short8*)(As + (wm * 64 + f * 16 + (lane & 15)) * 64 + koff);
        b[f] = *(const short8*)(Bs + (wn * 64 + f * 16 + (lane & 15)) * 64 + koff);
      }
#pragma unroll
      for (int fm = 0; fm < 4; fm++)
#pragma unroll
        for (int fn = 0; fn < 4; fn++)
          acc[fm][fn] = __builtin_amdgcn_mfma_f32_16x16x32_bf16(a[fm], b[fn], acc[fm][fn], 0, 0, 0);
    }
    __syncthreads();
  }

  // C/D layout (verified): col = lane&15, row = (lane>>4)*4 + reg
  u16* Cb = Cm + (size_t)bz * M * N;
  const int quad = lane >> 4, l15 = lane & 15;
#pragma unroll
  for (int fm = 0; fm < 4; fm++)
#pragma unroll
    for (int fn = 0; fn < 4; fn++)
#pragma unroll
      for (int r = 0; r < 4; r++) {
        int row = m0 + wm * 64 + fm * 16 + quad * 4 + r;
        int col = n0 + wn * 64 + fn * 16 + l15;
        Cb[(size_t)row * N + col] = f32_to_bf16(scale * acc[fm][fn][r]);
      }
}

// ---------------------------------------------------------------------------
// Softmax over 1024-wide rows of EP (bf16), in place. One WG per row.
// ---------------------------------------------------------------------------
__global__ __launch_bounds__(256) void softmax_kernel(u16* __restrict__ EP)
{
  const int r = blockIdx.x;               // 0..8191
  u16* row = EP + (size_t)r * 1024;
  const int t = threadIdx.x;
  const int lane = t & 63, wid = t >> 6;

  ushort4 hv = ((const ushort4*)row)[t];
  float e[4] = {bf16_to_f32(hv.x), bf16_to_f32(hv.y), bf16_to_f32(hv.z), bf16_to_f32(hv.w)};

  float mx = fmaxf(fmaxf(e[0], e[1]), fmaxf(e[2], e[3]));
#pragma unroll
  for (int off = 32; off > 0; off >>= 1) mx = fmaxf(mx, __shfl_xor(mx, off));
  __shared__ float redm[4];
  if (lane == 0) redm[wid] = mx;
  __syncthreads();
  mx = fmaxf(fmaxf(redm[0], redm[1]), fmaxf(redm[2], redm[3]));

  float s = 0.f;
#pragma unroll
  for (int i = 0; i < 4; i++) { e[i] = __expf(e[i] - mx); s += e[i]; }
#pragma unroll
  for (int off = 32; off > 0; off >>= 1) s += __shfl_xor(s, off);
  __shared__ float reds[4];
  if (lane == 0) reds[wid] = s;
  __syncthreads();
  s = reds[0] + reds[1] + reds[2] + reds[3];

  float inv = 1.0f / s;
  hv.x = f32_to_bf16(e[0] * inv);
  hv.y = f32_to_bf16(e[1] * inv);
  hv.z = f32_to_bf16(e[2] * inv);
  hv.w = f32_to_bf16(e[3] * inv);
  ((ushort4*)row)[t] = hv;
}

// ---------------------------------------------------------------------------
// K5: out[b][o][w][h] = gamma*(sum_cq Wo[o][cq]*OT[b][cq*128+(rem>>9)][rem&511] + bo[o]) + x
// ---------------------------------------------------------------------------
__global__ __launch_bounds__(256) void out_kernel(
    const float* __restrict__ x, const u16* __restrict__ OT,
    const float* __restrict__ Wo, const float* __restrict__ bo,
    const float* __restrict__ gammap, float* __restrict__ out)
{
  const int pix = blockIdx.x * 256 + threadIdx.x;   // 0..524287
  const int b = pix >> 16, rem = pix & 65535;
  const float g = gammap[0];

  const u16* otb = OT + (size_t)b * 524288;
  const int m = rem & 511;
  const int nbase = rem >> 9;                        // 0..127
  float oc[8];
#pragma unroll
  for (int cq = 0; cq < 8; cq++)
    oc[cq] = bf16_to_f32(otb[(size_t)(cq * 128 + nbase) * 512 + m]);

  const float* xb = x + (size_t)b * 4194304 + rem;
  float* ob = out + (size_t)b * 4194304 + rem;
#pragma unroll 4
  for (int o = 0; o < 64; o++) {
    float acc = bo[o];
#pragma unroll
    for (int cq = 0; cq < 8; cq++) acc = fmaf(Wo[o * 8 + cq], oc[cq], acc);
    ob[o * 65536] = fmaf(g, acc, xb[o * 65536]);
  }
}

// ---------------------------------------------------------------------------
extern "C" void kernel_launch(void* const* d_in, const int* in_sizes, int n_in,
                              void* d_out, int out_size, void* d_ws, size_t ws_size,
                              hipStream_t stream) {
  const float* x  = (const float*)d_in[0];
  const float* Wq = (const float*)d_in[1];
  const float* bq = (const float*)d_in[2];
  const float* Wk = (const float*)d_in[3];
  const float* bk = (const float*)d_in[4];
  const float* Wv = (const float*)d_in[5];
  const float* bv = (const float*)d_in[6];
  const float* Wo = (const float*)d_in[7];
  const float* bo = (const float*)d_in[8];
  const float* gm = (const float*)d_in[9];
  float* out = (float*)d_out;

  // workspace carve (40 MiB total): qt | kt | v | EP ; OT reuses qt (dead after G1)
  u16* qt = (u16*)d_ws;            // 8*1024*512 = 4194304 elems
  u16* kt = qt + 4194304;
  u16* vm = kt + 4194304;
  u16* EP = vm + 4194304;          // 8*1024*1024 elems
  u16* OT = qt;                    // reuse

  qkv_kernel<<<dim3(8, 8, 8), 1024, 0, stream>>>(x, Wq, bq, Wk, bk, Wv, bv, qt, kt, vm);
  // E = qt * kt^T / 32   -> EP bf16   (M=1024, N=1024, K=512)
  gemm_nt<<<dim3(8, 8, 8), 256, 0, stream>>>(qt, kt, EP, 1024, 1024, 512, 0.03125f);
  softmax_kernel<<<8192, 256, 0, stream>>>(EP);
  // OT[j][m] = P * v^T   (M=1024, N=512, K=1024)
  gemm_nt<<<dim3(4, 8, 8), 256, 0, stream>>>(EP, vm, OT, 1024, 512, 1024, 1.0f);
  out_kernel<<<2048, 256, 0, stream>>>(x, OT, Wo, bo, gm, out);
}

// Round 2
// 340.749 us; speedup vs baseline: 1.0316x; 1.0316x over previous
//
#include <hip/hip_runtime.h>
#include <stdint.h>

typedef unsigned short u16;
typedef unsigned int   u32;
typedef __attribute__((ext_vector_type(8))) short  short8;   // 8 x bf16 (4 VGPRs)
typedef __attribute__((ext_vector_type(4))) float  floatx4;  // MFMA acc

__device__ __forceinline__ u16 f32_to_bf16(float f) {
  u32 u = __builtin_bit_cast(u32, f);
  u = (u + 0x7fffu + ((u >> 16) & 1u)) >> 16;
  return (u16)u;
}
__device__ __forceinline__ float bf16_to_f32(u16 h) {
  u32 u = ((u32)h) << 16;
  return __builtin_bit_cast(float, u);
}

// async global->LDS, 16B per lane. LDS dst = wave-uniform base + lane*16.
__device__ __forceinline__ void load_lds16(const u16* g, u16* l) {
  auto gp = (const __attribute__((address_space(1))) u32*)(uintptr_t)g;
  auto lp = (__attribute__((address_space(3))) u32*)(u32)(uintptr_t)l;
  __builtin_amdgcn_global_load_lds(gp, lp, 16, 0, 0);
}

// ---------------------------------------------------------------------------
// K1: fused QKV 1x1 conv + patch-token layout. (unchanged from R1)
// qt,kt: [b][n][m] bf16 ; v: [b][m][n] bf16
// ---------------------------------------------------------------------------
__global__ __launch_bounds__(1024) void qkv_kernel(
    const float* __restrict__ x,
    const float* __restrict__ Wq, const float* __restrict__ bq,
    const float* __restrict__ Wk, const float* __restrict__ bk,
    const float* __restrict__ Wv, const float* __restrict__ bv,
    u16* __restrict__ qt, u16* __restrict__ kt, u16* __restrict__ vm)
{
  __shared__ __align__(16) u16 qs[128 * 64];   // [nl][cq*8+mc]
  __shared__ __align__(16) u16 ks_[128 * 64];
  __shared__ __align__(16) u16 vs[64 * 128];   // [cq*8+mc][nl]

  const int wq = blockIdx.x;   // 0..7
  const int g  = blockIdx.y;   // 0..7
  const int b  = blockIdx.z;   // 0..7
  const int t  = threadIdx.x;
  const int lw = t >> 5, lh = t & 31;
  const int w  = wq * 32 + lw;
  const int h  = g * 16 + (lh & 15) + ((lh >> 4) << 7);
  const int nl = ((lh >> 3) & 1) * 64 + (lw & 7) * 8 + (lh & 7);  // 0..127
  const int mc = ((lw >> 3) << 1) + (lh >> 4);                    // 0..7

  float aq[8], ak[8], av[8];
#pragma unroll
  for (int i = 0; i < 8; i++) { aq[i] = 0.f; ak[i] = 0.f; av[i] = 0.f; }

  const float* xp = x + (size_t)b * 64 * 65536 + w * 256 + h;
#pragma unroll 4
  for (int c = 0; c < 64; c++) {
    float xv = xp[c * 65536];
#pragma unroll
    for (int cq = 0; cq < 8; cq++) {
      aq[cq] = fmaf(Wq[cq * 64 + c], xv, aq[cq]);
      ak[cq] = fmaf(Wk[cq * 64 + c], xv, ak[cq]);
      av[cq] = fmaf(Wv[cq * 64 + c], xv, av[cq]);
    }
  }
#pragma unroll
  for (int cq = 0; cq < 8; cq++) {
    qs[nl * 64 + cq * 8 + mc]  = f32_to_bf16(aq[cq] + bq[cq]);
    ks_[nl * 64 + cq * 8 + mc] = f32_to_bf16(ak[cq] + bk[cq]);
    vs[(cq * 8 + mc) * 128 + nl] = f32_to_bf16(av[cq] + bv[cq]);
  }
  __syncthreads();

  {
    const int nl2 = t >> 3, cq2 = t & 7;
    const size_t row = (size_t)b * 1024 + g * 128 + nl2;
    uint4 vq = *(const uint4*)(qs + nl2 * 64 + cq2 * 8);
    uint4 vk = *(const uint4*)(ks_ + nl2 * 64 + cq2 * 8);
    *(uint4*)(qt + row * 512 + cq2 * 64 + wq * 8) = vq;
    *(uint4*)(kt + row * 512 + cq2 * 64 + wq * 8) = vk;
  }
  {
    const int pr = t >> 4, l16 = t & 15;
    const int cq3 = pr >> 3, mc3 = pr & 7;
    const int mrow = cq3 * 64 + wq * 8 + mc3;
    uint4 vv = *(const uint4*)(vs + pr * 128 + l16 * 8);
    *(uint4*)(vm + ((size_t)b * 512 + mrow) * 1024 + g * 128 + l16 * 8) = vv;
  }
}

// ---------------------------------------------------------------------------
// NT GEMM: C[M][N] = scale * A[M][K] * B[N][K]^T   (bf16 in, fp32 acc)
// Tile BM(=FMW*32) x 128, BK=64. LDS XOR-swizzled: logical 16B-chunk c of
// row r lives at physical chunk c^(r&7). Staging swizzles the GLOBAL source
// chunk (LDS dst of global_load_lds is fixed at base+lane*16); readers XOR
// the chunk index by lane&7. 16-way bank conflict -> 2-way (free).
// ---------------------------------------------------------------------------
template <int FMW>
__global__ __launch_bounds__(256) void gemm_nt(
    const u16* __restrict__ A, const u16* __restrict__ Bm, u16* __restrict__ Cm,
    int M, int N, int K, float scale)
{
  constexpr int BM = FMW * 32;
  __shared__ __align__(16) u16 As[BM * 64];
  __shared__ __align__(16) u16 Bs[128 * 64];

  const int bn = blockIdx.x, bm = blockIdx.y, bz = blockIdx.z;
  const int t = threadIdx.x;
  const int lane = t & 63, wid = t >> 6;
  const int wm = wid & 1, wn = wid >> 1;
  const int m0 = bm * BM, n0 = bn * 128;

  const u16* Ab = A + (size_t)bz * M * K + (size_t)m0 * K;
  const u16* Bb = Bm + (size_t)bz * N * K + (size_t)n0 * K;

  floatx4 acc[FMW][4];
#pragma unroll
  for (int i = 0; i < FMW; i++)
#pragma unroll
    for (int j = 0; j < 4; j++) acc[i][j] = (floatx4){0.f, 0.f, 0.f, 0.f};

  const int srow = wid * 8 + (lane >> 3);                 // staging row in 32-row group
  const int scol = (((lane & 7) ^ ((lane >> 3) & 7)) << 3); // swizzled source chunk
  const int l15 = lane & 15, quad = lane >> 4;
  const int cxor = (l15 & 7) << 3;                        // reader chunk XOR (in elems)

  for (int k0 = 0; k0 < K; k0 += 64) {
#pragma unroll
    for (int i = 0; i < FMW; i++)
      load_lds16(Ab + (size_t)(i * 32 + srow) * K + k0 + scol, As + (i * 32 + wid * 8) * 64);
#pragma unroll
    for (int i = 0; i < 4; i++)
      load_lds16(Bb + (size_t)(i * 32 + srow) * K + k0 + scol, Bs + (i * 32 + wid * 8) * 64);
    __syncthreads();
#pragma unroll
    for (int ks = 0; ks < 2; ks++) {
      const int koff = (ks * 32 + quad * 8) ^ cxor;   // swizzled chunk read
      short8 a[FMW], b[4];
#pragma unroll
      for (int f = 0; f < FMW; f++)
        a[f] = *(const short8*)(As + (wm * FMW * 16 + f * 16 + l15) * 64 + koff);
#pragma unroll
      for (int f = 0; f < 4; f++)
        b[f] = *(const short8*)(Bs + (wn * 64 + f * 16 + l15) * 64 + koff);
#pragma unroll
      for (int fm = 0; fm < FMW; fm++)
#pragma unroll
        for (int fn = 0; fn < 4; fn++)
          acc[fm][fn] = __builtin_amdgcn_mfma_f32_16x16x32_bf16(a[fm], b[fn], acc[fm][fn], 0, 0, 0);
    }
    __syncthreads();
  }

  // C/D layout (verified): col = lane&15, row = (lane>>4)*4 + reg
  u16* Cb = Cm + (size_t)bz * M * N;
#pragma unroll
  for (int fm = 0; fm < FMW; fm++)
#pragma unroll
    for (int fn = 0; fn < 4; fn++)
#pragma unroll
      for (int r = 0; r < 4; r++) {
        int row = m0 + wm * FMW * 16 + fm * 16 + quad * 4 + r;
        int col = n0 + wn * 64 + fn * 16 + l15;
        Cb[(size_t)row * N + col] = f32_to_bf16(scale * acc[fm][fn][r]);
      }
}

// ---------------------------------------------------------------------------
// Softmax over 1024-wide rows of EP (bf16), in place. One WG per row.
// ---------------------------------------------------------------------------
__global__ __launch_bounds__(256) void softmax_kernel(u16* __restrict__ EP)
{
  const int r = blockIdx.x;               // 0..8191
  u16* row = EP + (size_t)r * 1024;
  const int t = threadIdx.x;
  const int lane = t & 63, wid = t >> 6;

  ushort4 hv = ((const ushort4*)row)[t];
  float e[4] = {bf16_to_f32(hv.x), bf16_to_f32(hv.y), bf16_to_f32(hv.z), bf16_to_f32(hv.w)};

  float mx = fmaxf(fmaxf(e[0], e[1]), fmaxf(e[2], e[3]));
#pragma unroll
  for (int off = 32; off > 0; off >>= 1) mx = fmaxf(mx, __shfl_xor(mx, off));
  __shared__ float redm[4];
  if (lane == 0) redm[wid] = mx;
  __syncthreads();
  mx = fmaxf(fmaxf(redm[0], redm[1]), fmaxf(redm[2], redm[3]));

  float s = 0.f;
#pragma unroll
  for (int i = 0; i < 4; i++) { e[i] = __expf(e[i] - mx); s += e[i]; }
#pragma unroll
  for (int off = 32; off > 0; off >>= 1) s += __shfl_xor(s, off);
  __shared__ float reds[4];
  if (lane == 0) reds[wid] = s;
  __syncthreads();
  s = reds[0] + reds[1] + reds[2] + reds[3];

  float inv = 1.0f / s;
  hv.x = f32_to_bf16(e[0] * inv);
  hv.y = f32_to_bf16(e[1] * inv);
  hv.z = f32_to_bf16(e[2] * inv);
  hv.w = f32_to_bf16(e[3] * inv);
  ((ushort4*)row)[t] = hv;
}

// ---------------------------------------------------------------------------
// K5: out = gamma*(Wo . OT + bo) + x   (coalesced over pixels)
// ---------------------------------------------------------------------------
__global__ __launch_bounds__(256) void out_kernel(
    const float* __restrict__ x, const u16* __restrict__ OT,
    const float* __restrict__ Wo, const float* __restrict__ bo,
    const float* __restrict__ gammap, float* __restrict__ out)
{
  const int pix = blockIdx.x * 256 + threadIdx.x;   // 0..524287
  const int b = pix >> 16, rem = pix & 65535;
  const float g = gammap[0];

  const u16* otb = OT + (size_t)b * 524288;
  const int m = rem & 511;
  const int nbase = rem >> 9;                        // 0..127
  float oc[8];
#pragma unroll
  for (int cq = 0; cq < 8; cq++)
    oc[cq] = bf16_to_f32(otb[(size_t)(cq * 128 + nbase) * 512 + m]);

  const float* xb = x + (size_t)b * 4194304 + rem;
  float* ob = out + (size_t)b * 4194304 + rem;
#pragma unroll 4
  for (int o = 0; o < 64; o++) {
    float acc = bo[o];
#pragma unroll
    for (int cq = 0; cq < 8; cq++) acc = fmaf(Wo[o * 8 + cq], oc[cq], acc);
    ob[o * 65536] = fmaf(g, acc, xb[o * 65536]);
  }
}

// ---------------------------------------------------------------------------
extern "C" void kernel_launch(void* const* d_in, const int* in_sizes, int n_in,
                              void* d_out, int out_size, void* d_ws, size_t ws_size,
                              hipStream_t stream) {
  const float* x  = (const float*)d_in[0];
  const float* Wq = (const float*)d_in[1];
  const float* bq = (const float*)d_in[2];
  const float* Wk = (const float*)d_in[3];
  const float* bk = (const float*)d_in[4];
  const float* Wv = (const float*)d_in[5];
  const float* bv = (const float*)d_in[6];
  const float* Wo = (const float*)d_in[7];
  const float* bo = (const float*)d_in[8];
  const float* gm = (const float*)d_in[9];
  float* out = (float*)d_out;

  // workspace carve: qt | kt | v | EP ; OT reuses qt (dead after gemm1)
  u16* qt = (u16*)d_ws;            // 8*1024*512
  u16* kt = qt + 4194304;
  u16* vm = kt + 4194304;
  u16* EP = vm + 4194304;          // 8*1024*1024
  u16* OT = qt;                    // reuse

  qkv_kernel<<<dim3(8, 8, 8), 1024, 0, stream>>>(x, Wq, bq, Wk, bk, Wv, bv, qt, kt, vm);
  // E = qt * kt^T / 32   (M=1024, N=1024, K=512), 128x128 tiles -> 512 blocks
  gemm_nt<4><<<dim3(8, 8, 8), 256, 0, stream>>>(qt, kt, EP, 1024, 1024, 512, 0.03125f);
  softmax_kernel<<<8192, 256, 0, stream>>>(EP);
  // OT[j][m] = P * v^T   (M=1024, N=512, K=1024), 64x128 tiles -> 512 blocks
  gemm_nt<2><<<dim3(4, 16, 8), 256, 0, stream>>>(EP, vm, OT, 1024, 512, 1024, 1.0f);
  out_kernel<<<2048, 256, 0, stream>>>(x, OT, Wo, bo, gm, out);
}